// Round 1
// baseline (2274.650 us; speedup 1.0000x reference)
//
#include <hip/hip_runtime.h>
#include <math.h>

// DotProductAttention: B=32, L=2048, D=64, fp32, per-batch key-length mask.
// Round 0: correctness-first fp32 flash-attention.
//  - 1 wave (64 threads) per block; thread t owns query row (blockIdx-derived).
//  - Online softmax over K tiles of KT=32 rows staged in LDS.
//  - Mask: k >= valid_len[b] -> score -1e6 (exp underflows to 0, matches ref).
//  - Only iterate tiles that contain at least one valid key (saves ~half work).

#define BB 32
#define LL 2048
#define DD 64
#define QT 64   // query rows per block == block threads
#define KT 32   // key rows per tile

__global__ __launch_bounds__(64, 1) void attn_fp32_kernel(
    const float* __restrict__ Q, const float* __restrict__ K,
    const float* __restrict__ V, const int* __restrict__ vlen,
    float* __restrict__ O)
{
    __shared__ float Ks[KT][DD];
    __shared__ float Vs[KT][DD];

    const int nqt = LL / QT;               // 32 q-tiles per batch
    const int b   = blockIdx.x / nqt;
    const int qt  = blockIdx.x % nqt;
    const int q   = qt * QT + threadIdx.x; // this thread's query row
    const int valid = vlen[b];             // 1..L

    // Load q row into registers (16 x float4)
    const float4* Qp = reinterpret_cast<const float4*>(Q + ((size_t)b * LL + q) * DD);
    float4 qr[16];
    #pragma unroll
    for (int i = 0; i < 16; ++i) qr[i] = Qp[i];

    float acc[DD];
    #pragma unroll
    for (int d = 0; d < DD; ++d) acc[d] = 0.f;
    float m = -1e30f, l = 0.f;

    const float scale = 0.125f;            // 1/sqrt(64)
    const int ntiles = (valid + KT - 1) / KT;   // uniform across block

    const float4* Kg4 = reinterpret_cast<const float4*>(K + (size_t)b * LL * DD);
    const float4* Vg4 = reinterpret_cast<const float4*>(V + (size_t)b * LL * DD);
    float4* Ks4 = reinterpret_cast<float4*>(&Ks[0][0]);
    float4* Vs4 = reinterpret_cast<float4*>(&Vs[0][0]);

    for (int t = 0; t < ntiles; ++t) {
        __syncthreads();   // protect LDS reuse from previous tile
        // Stage K,V tile: KT*DD = 2048 floats = 512 float4; 64 threads -> 8 each
        const int tbase4 = t * KT * (DD / 4);
        #pragma unroll
        for (int i = 0; i < 8; ++i) {
            int idx = threadIdx.x + i * 64;
            Ks4[idx] = Kg4[tbase4 + idx];
            Vs4[idx] = Vg4[tbase4 + idx];
        }
        __syncthreads();

        const int kbase = t * KT;
        // Scores vs the 32 staged key rows (LDS broadcast reads)
        float s[KT];
        #pragma unroll
        for (int j = 0; j < KT; ++j) {
            const float4* kr = reinterpret_cast<const float4*>(&Ks[j][0]);
            float a0 = 0.f, a1 = 0.f, a2 = 0.f, a3 = 0.f;
            #pragma unroll
            for (int i = 0; i < 16; ++i) {
                float4 kv = kr[i];
                a0 += qr[i].x * kv.x;
                a1 += qr[i].y * kv.y;
                a2 += qr[i].z * kv.z;
                a3 += qr[i].w * kv.w;
            }
            float sc = (a0 + a1) + (a2 + a3);
            s[j] = (kbase + j < valid) ? sc * scale : -1e6f;
        }

        // Online softmax update
        float ms = s[0];
        #pragma unroll
        for (int j = 1; j < KT; ++j) ms = fmaxf(ms, s[j]);
        float mnew = fmaxf(m, ms);
        float corr = __expf(m - mnew);
        l *= corr;
        #pragma unroll
        for (int d = 0; d < DD; ++d) acc[d] *= corr;
        m = mnew;

        #pragma unroll
        for (int j = 0; j < KT; ++j) {
            float p = __expf(s[j] - mnew);
            l += p;
            const float4* vr = reinterpret_cast<const float4*>(&Vs[j][0]);
            #pragma unroll
            for (int i = 0; i < 16; ++i) {
                float4 vv = vr[i];
                acc[4 * i + 0] += p * vv.x;
                acc[4 * i + 1] += p * vv.y;
                acc[4 * i + 2] += p * vv.z;
                acc[4 * i + 3] += p * vv.w;
            }
        }
    }

    const float inv = 1.f / l;
    float4* Op = reinterpret_cast<float4*>(O + ((size_t)b * LL + q) * DD);
    #pragma unroll
    for (int i = 0; i < 16; ++i) {
        float4 o;
        o.x = acc[4 * i + 0] * inv;
        o.y = acc[4 * i + 1] * inv;
        o.z = acc[4 * i + 2] * inv;
        o.w = acc[4 * i + 3] * inv;
        Op[i] = o;
    }
}

extern "C" void kernel_launch(void* const* d_in, const int* in_sizes, int n_in,
                              void* d_out, int out_size, void* d_ws, size_t ws_size,
                              hipStream_t stream) {
    const float* Q = (const float*)d_in[0];
    const float* K = (const float*)d_in[1];
    const float* V = (const float*)d_in[2];
    const int* vlen = (const int*)d_in[3];
    float* O = (float*)d_out;

    dim3 grid(BB * (LL / QT));   // 32 * 32 = 1024 blocks
    dim3 block(QT);              // 64 threads = 1 wave
    attn_fp32_kernel<<<grid, block, 0, stream>>>(Q, K, V, vlen, O);
}

// Round 2
// 158.403 us; speedup vs baseline: 14.3599x; 14.3599x over previous
//
#include <hip/hip_runtime.h>
#include <math.h>

// DotProductAttention B=32, L=2048, D=64, fp32 IO, per-batch key-length mask.
// Round 1: bf16 MFMA flash-attention.
//  - 4 waves/block, Q-tile=64 (16 q-rows/wave), K-tile=64.
//  - QK^T and PV via mfma_f32_16x16x32_bf16; fp32 online softmax.
//  - K staged [k][d], V staged transposed [d][k], P re-laid out via
//    wave-private LDS; all LDS rows XOR-swizzled (elem ^= (row&7)<<3)
//    to kill the 128B-row bank conflict (guide §6 G4).
//  - Masked keys -> s=-1e30 -> exp underflows to 0 (== ref's -1e6 fill).

#define BB 32
#define LL 2048
#define DD 64
#define QBLK 64
#define KBLK 64

typedef __attribute__((ext_vector_type(8))) short bf16x8;
typedef __attribute__((ext_vector_type(4))) float f32x4;

static __device__ __forceinline__ short f2bf(float f) {
    union { float f; unsigned u; } v; v.f = f;
    unsigned r = (v.u + 0x7FFFu + ((v.u >> 16) & 1u)) >> 16;
    return (short)r;
}

__global__ __launch_bounds__(256, 2) void attn_mfma_kernel(
    const float* __restrict__ Q, const float* __restrict__ K,
    const float* __restrict__ V, const int* __restrict__ vlen,
    float* __restrict__ O)
{
    __shared__ __align__(16) short Ks[KBLK * DD];      // [k][d], swizzled
    __shared__ __align__(16) short Vt[DD * KBLK];      // [d][k], swizzled
    __shared__ __align__(16) short Pl[4 * 16 * KBLK];  // per-wave [q][k], swizzled

    const int tid  = threadIdx.x;
    const int wid  = tid >> 6;
    const int lane = tid & 63;
    const int lq   = lane & 15;   // "col" index in frag layouts
    const int lg   = lane >> 4;   // 4-lane-group id 0..3

    const int nqt = LL / QBLK;            // 32
    const int b   = blockIdx.x / nqt;
    const int qt  = blockIdx.x % nqt;
    const int qbase = qt * QBLK + wid * 16;
    const int valid = vlen[b];

    // ---- load Q A-fragments (held in regs): lane holds Q[qbase+lq][dstep*32 + lg*8 .. +7]
    bf16x8 qf[2];
    {
        const float* Qr = Q + ((size_t)b * LL + qbase + lq) * DD;
        #pragma unroll
        for (int ds_ = 0; ds_ < 2; ++ds_) {
            const float4* p4 = reinterpret_cast<const float4*>(Qr + ds_ * 32 + lg * 8);
            float4 a = p4[0], c = p4[1];
            bf16x8 f;
            f[0] = f2bf(a.x); f[1] = f2bf(a.y); f[2] = f2bf(a.z); f[3] = f2bf(a.w);
            f[4] = f2bf(c.x); f[5] = f2bf(c.y); f[6] = f2bf(c.z); f[7] = f2bf(c.w);
            qf[ds_] = f;
        }
    }

    f32x4 acc[4];                 // O accumulator: acc[n][r] -> q=lg*4+r, d=n*16+lq
    #pragma unroll
    for (int n = 0; n < 4; ++n) acc[n] = (f32x4){0.f, 0.f, 0.f, 0.f};
    float m_[4], l_[4];
    #pragma unroll
    for (int r = 0; r < 4; ++r) { m_[r] = -1e30f; l_[r] = 0.f; }

    const int ntiles = (valid + KBLK - 1) / KBLK;
    const float4* Kg4 = reinterpret_cast<const float4*>(K + (size_t)b * LL * DD);
    const float4* Vg4 = reinterpret_cast<const float4*>(V + (size_t)b * LL * DD);

    for (int kt = 0; kt < ntiles; ++kt) {
        __syncthreads();          // protect LDS reuse from previous tile
        // ---- stage K (row-major) and V (transposed), fp32->bf16, swizzled
        const int base4 = kt * KBLK * (DD / 4);
        #pragma unroll
        for (int i = 0; i < 4; ++i) {
            int idx = tid + i * 256;          // 0..1023
            int kr  = idx >> 4;               // key row 0..63
            int dc  = (idx & 15) * 4;         // d col 0,4,..60
            float4 kv = Kg4[base4 + idx];
            unsigned lo = (unsigned short)f2bf(kv.x) | ((unsigned)(unsigned short)f2bf(kv.y) << 16);
            unsigned hi = (unsigned short)f2bf(kv.z) | ((unsigned)(unsigned short)f2bf(kv.w) << 16);
            int e = (kr * 64 + dc) ^ ((kr & 7) << 3);
            *reinterpret_cast<unsigned*>(&Ks[e])     = lo;
            *reinterpret_cast<unsigned*>(&Ks[e + 2]) = hi;
            float4 vv = Vg4[base4 + idx];
            Vt[((dc + 0) * 64 + kr) ^ (((dc + 0) & 7) << 3)] = f2bf(vv.x);
            Vt[((dc + 1) * 64 + kr) ^ (((dc + 1) & 7) << 3)] = f2bf(vv.y);
            Vt[((dc + 2) * 64 + kr) ^ (((dc + 2) & 7) << 3)] = f2bf(vv.z);
            Vt[((dc + 3) * 64 + kr) ^ (((dc + 3) & 7) << 3)] = f2bf(vv.w);
        }
        __syncthreads();

        // ---- QK^T: S[q][k] tiles, q rows = wave's 16, k in 4 chunks of 16
        f32x4 s[4];
        #pragma unroll
        for (int t = 0; t < 4; ++t) {
            f32x4 a = (f32x4){0.f, 0.f, 0.f, 0.f};
            const int krow = t * 16 + lq;
            #pragma unroll
            for (int ds_ = 0; ds_ < 2; ++ds_) {
                int e = (krow * 64 + ds_ * 32 + lg * 8) ^ ((krow & 7) << 3);
                bf16x8 kf = *reinterpret_cast<const bf16x8*>(&Ks[e]);
                a = __builtin_amdgcn_mfma_f32_16x16x32_bf16(qf[ds_], kf, a, 0, 0, 0);
            }
            s[t] = a;
        }

        // ---- mask + scale + online softmax (row q = lg*4 + r)
        float rowmax[4];
        #pragma unroll
        for (int r = 0; r < 4; ++r) {
            float mx = -1e30f;
            #pragma unroll
            for (int t = 0; t < 4; ++t) {
                int kg = kt * KBLK + t * 16 + lq;
                float v = (kg < valid) ? s[t][r] * 0.125f : -1e30f;
                s[t][r] = v;
                mx = fmaxf(mx, v);
            }
            #pragma unroll
            for (int off = 1; off < 16; off <<= 1)
                mx = fmaxf(mx, __shfl_xor(mx, off, 64));
            rowmax[r] = mx;
        }
        float corr[4];
        #pragma unroll
        for (int r = 0; r < 4; ++r) {
            float mnew = fmaxf(m_[r], rowmax[r]);
            corr[r] = __expf(m_[r] - mnew);
            m_[r] = mnew;
            l_[r] *= corr[r];
        }
        #pragma unroll
        for (int n = 0; n < 4; ++n) {
            acc[n][0] *= corr[0]; acc[n][1] *= corr[1];
            acc[n][2] *= corr[2]; acc[n][3] *= corr[3];
        }
        #pragma unroll
        for (int r = 0; r < 4; ++r) {
            float ls = 0.f;
            #pragma unroll
            for (int t = 0; t < 4; ++t) {
                float p = __expf(s[t][r] - m_[r]);
                s[t][r] = p;
                ls += p;
            }
            #pragma unroll
            for (int off = 1; off < 16; off <<= 1)
                ls += __shfl_xor(ls, off, 64);
            l_[r] += ls;
        }

        // ---- P -> wave-private LDS (bf16, swizzled), then A-frag reads
        short* Pw = &Pl[wid * (16 * KBLK)];
        #pragma unroll
        for (int t = 0; t < 4; ++t) {
            #pragma unroll
            for (int r = 0; r < 4; ++r) {
                int qrow = lg * 4 + r;
                Pw[(qrow * 64 + t * 16 + lq) ^ ((qrow & 7) << 3)] = f2bf(s[t][r]);
            }
        }

        // ---- PV: O[q][d] += P(16xKBLK) * V(KBLKx64)
        #pragma unroll
        for (int ks_ = 0; ks_ < 2; ++ks_) {
            int pe = (lq * 64 + ks_ * 32 + lg * 8) ^ ((lq & 7) << 3);
            bf16x8 pf = *reinterpret_cast<const bf16x8*>(&Pw[pe]);
            #pragma unroll
            for (int n = 0; n < 4; ++n) {
                int drow = n * 16 + lq;
                int ve = (drow * 64 + ks_ * 32 + lg * 8) ^ ((drow & 7) << 3);
                bf16x8 vf = *reinterpret_cast<const bf16x8*>(&Vt[ve]);
                acc[n] = __builtin_amdgcn_mfma_f32_16x16x32_bf16(pf, vf, acc[n], 0, 0, 0);
            }
        }
    }

    // ---- epilogue: O = acc / l
    float inv[4];
    #pragma unroll
    for (int r = 0; r < 4; ++r) inv[r] = 1.f / l_[r];
    float* Ob = O + ((size_t)b * LL + qbase) * DD;
    #pragma unroll
    for (int n = 0; n < 4; ++n) {
        #pragma unroll
        for (int r = 0; r < 4; ++r) {
            Ob[(size_t)(lg * 4 + r) * DD + n * 16 + lq] = acc[n][r] * inv[r];
        }
    }
}

extern "C" void kernel_launch(void* const* d_in, const int* in_sizes, int n_in,
                              void* d_out, int out_size, void* d_ws, size_t ws_size,
                              hipStream_t stream) {
    const float* Q = (const float*)d_in[0];
    const float* K = (const float*)d_in[1];
    const float* V = (const float*)d_in[2];
    const int* vlen = (const int*)d_in[3];
    float* O = (float*)d_out;

    dim3 grid(BB * (LL / QBLK));   // 1024 blocks
    dim3 block(256);               // 4 waves
    attn_mfma_kernel<<<grid, block, 0, stream>>>(Q, K, V, vlen, O);
}